// Round 4
// baseline (1022.831 us; speedup 1.0000x reference)
//
#include <hip/hip_runtime.h>
#include <hip/hip_bf16.h>

#define B_SZ 16384
#define D_SZ 1024
#define H_SZ 2048
#define C_SZ 128
#define T_STEPS 20

typedef __attribute__((ext_vector_type(4))) float f32x4;
typedef __attribute__((ext_vector_type(8))) short bf16x8;

__device__ __forceinline__ void gl_lds16(const void* g, void* l) {
    __builtin_amdgcn_global_load_lds(
        (const __attribute__((address_space(1))) unsigned int*)g,
        (__attribute__((address_space(3))) unsigned int*)l, 16, 0, 0);
}

__device__ __forceinline__ unsigned int lif_mask(float i1) {
    float u = 0.0f;
    unsigned int m = 0;
    #pragma unroll
    for (int t = 0; t < T_STEPS; ++t) {
        u = __fadd_rn(__fmul_rn(0.9f, u), i1);   // match np: separate mul, add
        if (u >= 1.0f) { m |= (1u << t); u = 0.0f; }
    }
    return m;
}

// ---------------- generic fp32 -> 2 bf16 planes splitter (RNE hi, RNE mid) ----------
// processes 4 floats/thread; n = element count (multiple of 1024)
__global__ void k_split2(const float* __restrict__ src, unsigned short* __restrict__ dst, int n) {
    int i = blockIdx.x * blockDim.x + threadIdx.x;   // float4 index
    float4 v = reinterpret_cast<const float4*>(src)[i];
    float f[4] = {v.x, v.y, v.z, v.w};
    unsigned short h[4], m[4];
    #pragma unroll
    for (int j = 0; j < 4; ++j) {
        __hip_bfloat16 hb = __float2bfloat16(f[j]);
        h[j] = __bfloat16_as_ushort(hb);
        m[j] = __bfloat16_as_ushort(__float2bfloat16(f[j] - __bfloat162float(hb)));
    }
    reinterpret_cast<ushort4*>(dst)[i] = make_ushort4(h[0], h[1], h[2], h[3]);
    reinterpret_cast<ushort4*>(dst + n)[i] = make_ushort4(m[0], m[1], m[2], m[3]);
}

// x trunc-hi / RNE-mid split (fallback path only)
#define SPLIT2(fe, fo, HW, MW) { \
    unsigned ue = __float_as_uint(fe), uo = __float_as_uint(fo); \
    HW = (uo & 0xffff0000u) | (ue >> 16); \
    float re = (fe) - __uint_as_float(ue & 0xffff0000u); \
    float ro = (fo) - __uint_as_float(uo & 0xffff0000u); \
    MW = (unsigned)__bfloat16_as_ushort(__float2bfloat16(re)) | \
         ((unsigned)__bfloat16_as_ushort(__float2bfloat16(ro)) << 16); }

// ---------------- K1 (pre-split path): i1 = x@W1^T + b1 via 2-split bf16 MFMA --------
// A = W1 planes, B = x planes, both staged via global_load_lds (pre-swizzled source).
// 128x128 tile, 4 waves (2x2), BK=32. LDS row = 128 B [r][s][32 bf16], XOR ^ (r&7)<<4.
__global__ __launch_bounds__(256, 4) void k_gemm1_ps(
    const unsigned short* __restrict__ xs,    // [2][B][D]
    const unsigned short* __restrict__ w1s,   // [2][H][D]
    const float* __restrict__ b1,
    unsigned short* __restrict__ M16,
    unsigned char* __restrict__ M4,
    unsigned int* __restrict__ spike_count)
{
    __shared__ char lds[32768];   // [0,16K): W1 tile, [16K,32K): x tile
    const int tid  = threadIdx.x;
    const int wv   = tid >> 6;
    const int lane = tid & 63;
    const int l15  = lane & 15;
    const int g    = lane >> 4;
    const int wr   = wv >> 1;
    const int wc   = wv & 1;
    const int hb0  = blockIdx.x * 128;
    const int bb0  = blockIdx.y * 128;

    f32x4 acc[4][4];
    #pragma unroll
    for (int i = 0; i < 4; ++i)
        #pragma unroll
        for (int j = 0; j < 4; ++j)
            acc[i][j] = (f32x4){0.f, 0.f, 0.f, 0.f};

    for (int k0 = 0; k0 < D_SZ; k0 += 32) {
        __syncthreads();
        #pragma unroll
        for (int i = 0; i < 4; ++i) {   // W1 region
            int alin = i * 4096 + wv * 1024 + lane * 16;
            int r  = alin >> 7;
            int o  = alin ^ ((r & 7) << 4);
            int s  = (o >> 6) & 1;
            int kk = (o & 63) >> 1;
            gl_lds16(w1s + ((size_t)s * H_SZ + hb0 + r) * D_SZ + k0 + kk,
                     lds + (i * 4096 + wv * 1024));
        }
        #pragma unroll
        for (int i = 0; i < 4; ++i) {   // x region
            int alin = i * 4096 + wv * 1024 + lane * 16;
            int r  = alin >> 7;
            int o  = alin ^ ((r & 7) << 4);
            int s  = (o >> 6) & 1;
            int kk = (o & 63) >> 1;
            gl_lds16(xs + ((size_t)s * B_SZ + bb0 + r) * D_SZ + k0 + kk,
                     lds + (16384 + i * 4096 + wv * 1024));
        }
        __syncthreads();

        bf16x8 Xh[4], Xm[4];
        #pragma unroll
        for (int n = 0; n < 4; ++n) {
            int c  = wc * 64 + n * 16 + l15;
            int sw = (c & 7) << 4;
            Xh[n] = *reinterpret_cast<const bf16x8*>(lds + (16384 + ((c * 128 + g * 16) ^ sw)));
            Xm[n] = *reinterpret_cast<const bf16x8*>(lds + (16384 + ((c * 128 + 64 + g * 16) ^ sw)));
        }
        #pragma unroll
        for (int m = 0; m < 4; ++m) {
            int r  = wr * 64 + m * 16 + l15;
            int sw = (r & 7) << 4;
            bf16x8 Wh = *reinterpret_cast<const bf16x8*>(lds + ((r * 128 + g * 16) ^ sw));
            bf16x8 Wm = *reinterpret_cast<const bf16x8*>(lds + ((r * 128 + 64 + g * 16) ^ sw));
            #pragma unroll
            for (int n = 0; n < 4; ++n) {
                acc[m][n] = __builtin_amdgcn_mfma_f32_16x16x32_bf16(Wh, Xh[n], acc[m][n], 0, 0, 0);
                acc[m][n] = __builtin_amdgcn_mfma_f32_16x16x32_bf16(Wh, Xm[n], acc[m][n], 0, 0, 0);
                acc[m][n] = __builtin_amdgcn_mfma_f32_16x16x32_bf16(Wm, Xh[n], acc[m][n], 0, 0, 0);
            }
        }
    }

    int spikes = 0;
    #pragma unroll
    for (int m = 0; m < 4; ++m) {
        const int h0l = hb0 + wr * 64 + m * 16 + g * 4;
        float4 bias = *reinterpret_cast<const float4*>(b1 + h0l);
        #pragma unroll
        for (int n = 0; n < 4; ++n) {
            const int b = bb0 + wc * 64 + n * 16 + l15;
            unsigned mk0 = lif_mask(acc[m][n][0] + bias.x);
            unsigned mk1 = lif_mask(acc[m][n][1] + bias.y);
            unsigned mk2 = lif_mask(acc[m][n][2] + bias.z);
            unsigned mk3 = lif_mask(acc[m][n][3] + bias.w);
            spikes += __popc(mk0) + __popc(mk1) + __popc(mk2) + __popc(mk3);
            *reinterpret_cast<uint2*>(M16 + (size_t)b * H_SZ + h0l) =
                make_uint2((mk0 & 0xffffu) | (mk1 << 16),
                           (mk2 & 0xffffu) | (mk3 << 16));
            *reinterpret_cast<unsigned int*>(M4 + (size_t)b * H_SZ + h0l) =
                (mk0 >> 16) | ((mk1 >> 16) << 8) | ((mk2 >> 16) << 16) | ((mk3 >> 16) << 24);
        }
    }
    #pragma unroll
    for (int off = 32; off > 0; off >>= 1)
        spikes += __shfl_down(spikes, off);
    if (lane == 0)
        atomicAdd(spike_count, (unsigned int)spikes);
}

// ---------------- K1 (fallback, no x pre-split): round-3 kernel verbatim ------------
__global__ __launch_bounds__(256) void k_gemm1_mfma(
    const float* __restrict__ x,
    const unsigned short* __restrict__ w1s,
    const float* __restrict__ b1,
    unsigned short* __restrict__ M16,
    unsigned char* __restrict__ M4,
    unsigned int* __restrict__ spike_count)
{
    __shared__ char lds[32768];
    const int tid  = threadIdx.x;
    const int wv   = tid >> 6;
    const int lane = tid & 63;
    const int l15  = lane & 15;
    const int g    = lane >> 4;
    const int wr   = wv >> 1;
    const int wc   = wv & 1;
    const int hb0  = blockIdx.x * 128;
    const int bb0  = blockIdx.y * 128;

    const int ar   = tid >> 1;
    const int ac0  = (tid & 1) * 16;
    const float* xrow = x + (size_t)(bb0 + ar) * D_SZ + ac0;
    const int asw   = (ar & 7) << 4;
    const int lbase = 16384 + ar * 128 + ac0 * 2;

    f32x4 acc[4][4];
    #pragma unroll
    for (int i = 0; i < 4; ++i)
        #pragma unroll
        for (int j = 0; j < 4; ++j)
            acc[i][j] = (f32x4){0.f, 0.f, 0.f, 0.f};

    for (int k0 = 0; k0 < D_SZ; k0 += 32) {
        float4 av0 = *reinterpret_cast<const float4*>(xrow + k0);
        float4 av1 = *reinterpret_cast<const float4*>(xrow + k0 + 4);
        float4 av2 = *reinterpret_cast<const float4*>(xrow + k0 + 8);
        float4 av3 = *reinterpret_cast<const float4*>(xrow + k0 + 12);
        __syncthreads();
        #pragma unroll
        for (int i = 0; i < 4; ++i) {
            int o   = i * 4096 + wv * 1024 + lane * 16;
            int col = o >> 7;
            int p   = o ^ ((col & 7) << 4);
            int s   = (p >> 6) & 1;
            int kk  = (p & 63) >> 1;
            gl_lds16(w1s + ((size_t)s * H_SZ + hb0 + col) * D_SZ + k0 + kk,
                     lds + (i * 4096 + wv * 1024));
        }
        {
            uint4 hwv, hwv2, mwv, mwv2;
            SPLIT2(av0.x, av0.y, hwv.x,  mwv.x);
            SPLIT2(av0.z, av0.w, hwv.y,  mwv.y);
            SPLIT2(av1.x, av1.y, hwv.z,  mwv.z);
            SPLIT2(av1.z, av1.w, hwv.w,  mwv.w);
            SPLIT2(av2.x, av2.y, hwv2.x, mwv2.x);
            SPLIT2(av2.z, av2.w, hwv2.y, mwv2.y);
            SPLIT2(av3.x, av3.y, hwv2.z, mwv2.z);
            SPLIT2(av3.z, av3.w, hwv2.w, mwv2.w);
            *reinterpret_cast<uint4*>(lds + ((lbase)      ^ asw)) = hwv;
            *reinterpret_cast<uint4*>(lds + ((lbase + 16) ^ asw)) = hwv2;
            *reinterpret_cast<uint4*>(lds + ((lbase + 64) ^ asw)) = mwv;
            *reinterpret_cast<uint4*>(lds + ((lbase + 80) ^ asw)) = mwv2;
        }
        __syncthreads();

        bf16x8 Xh[4], Xm[4];
        #pragma unroll
        for (int n = 0; n < 4; ++n) {
            int c  = wc * 64 + n * 16 + l15;
            int sw = (c & 7) << 4;
            Xh[n] = *reinterpret_cast<const bf16x8*>(lds + (16384 + ((c * 128 + g * 16) ^ sw)));
            Xm[n] = *reinterpret_cast<const bf16x8*>(lds + (16384 + ((c * 128 + 64 + g * 16) ^ sw)));
        }
        #pragma unroll
        for (int m = 0; m < 4; ++m) {
            int r  = wr * 64 + m * 16 + l15;
            int sw = (r & 7) << 4;
            bf16x8 Wh = *reinterpret_cast<const bf16x8*>(lds + ((r * 128 + g * 16) ^ sw));
            bf16x8 Wm = *reinterpret_cast<const bf16x8*>(lds + ((r * 128 + 64 + g * 16) ^ sw));
            #pragma unroll
            for (int n = 0; n < 4; ++n) {
                acc[m][n] = __builtin_amdgcn_mfma_f32_16x16x32_bf16(Wh, Xh[n], acc[m][n], 0, 0, 0);
                acc[m][n] = __builtin_amdgcn_mfma_f32_16x16x32_bf16(Wh, Xm[n], acc[m][n], 0, 0, 0);
                acc[m][n] = __builtin_amdgcn_mfma_f32_16x16x32_bf16(Wm, Xh[n], acc[m][n], 0, 0, 0);
            }
        }
    }

    int spikes = 0;
    #pragma unroll
    for (int m = 0; m < 4; ++m) {
        const int h0l = hb0 + wr * 64 + m * 16 + g * 4;
        float4 bias = *reinterpret_cast<const float4*>(b1 + h0l);
        #pragma unroll
        for (int n = 0; n < 4; ++n) {
            const int b = bb0 + wc * 64 + n * 16 + l15;
            unsigned mk0 = lif_mask(acc[m][n][0] + bias.x);
            unsigned mk1 = lif_mask(acc[m][n][1] + bias.y);
            unsigned mk2 = lif_mask(acc[m][n][2] + bias.z);
            unsigned mk3 = lif_mask(acc[m][n][3] + bias.w);
            spikes += __popc(mk0) + __popc(mk1) + __popc(mk2) + __popc(mk3);
            *reinterpret_cast<uint2*>(M16 + (size_t)b * H_SZ + h0l) =
                make_uint2((mk0 & 0xffffu) | (mk1 << 16),
                           (mk2 & 0xffffu) | (mk3 << 16));
            *reinterpret_cast<unsigned int*>(M4 + (size_t)b * H_SZ + h0l) =
                (mk0 >> 16) | ((mk1 >> 16) << 8) | ((mk2 >> 16) << 16) | ((mk3 >> 16) << 24);
        }
    }
    #pragma unroll
    for (int off = 32; off > 0; off >>= 1)
        spikes += __shfl_down(spikes, off);
    if (lane == 0)
        atomicAdd(spike_count, (unsigned int)spikes);
}

// ---------------- K2: layer 2, t-split waves + fused LIF epilogue ----------------
// 512 thr = 8 waves. Wave (tg = w>>1, ch = w&1): 5 timesteps x 64 cols, 16 b-rows.
// acc[4 n-tiles][5 t] = 80 VGPRs. LDS: union{ staging 20.5 KB, transpose 43 KB }.
#define STG(s, c, k) sm_u16[(((s) * 128 + (c)) * 40) + (k)]
#define TLV(b, c, t) sm_f32[(((b) * 32 + (c)) * 21) + (t)]
__global__ __launch_bounds__(512, 4) void k_layer2_mfma(
    const unsigned short* __restrict__ M16,
    const unsigned char* __restrict__ M4,
    const unsigned short* __restrict__ W2p,   // [2][C][H]
    const float* __restrict__ b2,
    float* __restrict__ out)
{
    __shared__ __align__(16) char smem[43008];
    unsigned short* sm_u16 = (unsigned short*)smem;
    float*          sm_f32 = (float*)smem;

    const int tid  = threadIdx.x;
    const int w    = tid >> 6;
    const int tg   = w >> 1;          // t-group: t in [tg*5, tg*5+5)
    const int ch   = w & 1;           // c-half: cols [ch*64, ch*64+64)
    const int lane = tid & 63;
    const int l15  = lane & 15;
    const int g    = lane >> 4;
    const int b0   = blockIdx.x * 16;
    const int t0   = tg * 5;
    const int cb   = ch * 64;

    f32x4 acc[4][5];
    #pragma unroll
    for (int n = 0; n < 4; ++n)
        #pragma unroll
        for (int t = 0; t < 5; ++t)
            acc[n][t] = (f32x4){0.f, 0.f, 0.f, 0.f};

    const unsigned short* m16row = M16 + (size_t)(b0 + l15) * H_SZ;
    const unsigned char*  m4row  = M4  + (size_t)(b0 + l15) * H_SZ;

    for (int kt = 0; kt < 64; ++kt) {
        const int h0 = kt * 32;
        uint4 w16 = *reinterpret_cast<const uint4*>(m16row + h0 + g * 8);
        uint2 w4 = make_uint2(0u, 0u);
        if (tg == 3)
            w4 = *reinterpret_cast<const uint2*>(m4row + h0 + g * 8);

        __syncthreads();
        // stage W2p tile: 2 planes x 128 c x 32 h (pad-40 rows), 2 x 16B per thread
        #pragma unroll
        for (int i = 0; i < 2; ++i) {
            int q   = tid * 2 + i;        // 16B units
            int row = q >> 2;             // 0..255
            int s   = row >> 7;
            int c   = row & 127;
            int kk  = (q & 3) * 8;
            uint4 v = *reinterpret_cast<const uint4*>(
                W2p + ((size_t)s * C_SZ + c) * H_SZ + h0 + kk);
            *reinterpret_cast<uint4*>(&STG(s, c, kk)) = v;
        }
        __syncthreads();

        bf16x8 bf[2][4];
        #pragma unroll
        for (int s = 0; s < 2; ++s)
            #pragma unroll
            for (int nt = 0; nt < 4; ++nt)
                bf[s][nt] = *reinterpret_cast<const bf16x8*>(&STG(s, cb + nt * 16 + l15, g * 8));

        #pragma unroll
        for (int tl_ = 0; tl_ < 5; ++tl_) {
            const int t = t0 + tl_;
            union { bf16x8 v; unsigned int u[4]; } A;
            if (t < 16) {
                A.u[0] = ((w16.x >> t) & 0x10001u) * 0x3F80u;
                A.u[1] = ((w16.y >> t) & 0x10001u) * 0x3F80u;
                A.u[2] = ((w16.z >> t) & 0x10001u) * 0x3F80u;
                A.u[3] = ((w16.w >> t) & 0x10001u) * 0x3F80u;
            } else {
                const int tt = t - 16;
                unsigned x0 = (w4.x >> tt)        & 0x101u;
                unsigned x1 = (w4.x >> (16 + tt)) & 0x101u;
                unsigned x2 = (w4.y >> tt)        & 0x101u;
                unsigned x3 = (w4.y >> (16 + tt)) & 0x101u;
                A.u[0] = ((x0 * 0x0101u) & 0x10001u) * 0x3F80u;
                A.u[1] = ((x1 * 0x0101u) & 0x10001u) * 0x3F80u;
                A.u[2] = ((x2 * 0x0101u) & 0x10001u) * 0x3F80u;
                A.u[3] = ((x3 * 0x0101u) & 0x10001u) * 0x3F80u;
            }
            #pragma unroll
            for (int nt = 0; nt < 4; ++nt) {
                acc[nt][tl_] = __builtin_amdgcn_mfma_f32_16x16x32_bf16(A.v, bf[0][nt], acc[nt][tl_], 0, 0, 0);
                acc[nt][tl_] = __builtin_amdgcn_mfma_f32_16x16x32_bf16(A.v, bf[1][nt], acc[nt][tl_], 0, 0, 0);
            }
        }
    }

    // epilogue: 4 c-chunks of 32; transpose through LDS, then LIF per (b,c)
    #pragma unroll
    for (int q = 0; q < 4; ++q) {
        __syncthreads();
        if (ch == (q >> 1)) {
            #pragma unroll
            for (int u = 0; u < 2; ++u) {
                const int nt = (q & 1) * 2 + u;
                const int cl = nt * 16 + l15 - (q & 1) * 32;   // 0..31
                #pragma unroll
                for (int tl_ = 0; tl_ < 5; ++tl_)
                    #pragma unroll
                    for (int j = 0; j < 4; ++j)
                        TLV(g * 4 + j, cl, t0 + tl_) = acc[nt][tl_][j];
            }
        }
        __syncthreads();
        {
            const int cl = tid & 31;
            const int bl = tid >> 5;
            const int c  = q * 32 + cl;
            const float bias = b2[c];
            float u2 = 0.0f; int cnt = 0;
            #pragma unroll
            for (int t = 0; t < T_STEPS; ++t) {
                float X = TLV(bl, cl, t) + bias;
                u2 = __fadd_rn(__fmul_rn(0.9f, u2), X);
                if (u2 >= 1.0f) { cnt++; u2 = 0.0f; }
            }
            out[(size_t)(b0 + bl) * C_SZ + c] = (float)cnt / 20.0f;
        }
    }
}

// ---------------- K3: mean_spikes = total / (B * T) ----------------
__global__ void k_finalize(const unsigned int* __restrict__ spike_count, float* __restrict__ out) {
    out[(size_t)B_SZ * C_SZ] = (float)(*spike_count) / (float)((size_t)B_SZ * T_STEPS);
}

extern "C" void kernel_launch(void* const* d_in, const int* in_sizes, int n_in,
                              void* d_out, int out_size, void* d_ws, size_t ws_size,
                              hipStream_t stream) {
    const float* x  = (const float*)d_in[0];
    const float* W1 = (const float*)d_in[1];
    const float* b1 = (const float*)d_in[2];
    const float* W2 = (const float*)d_in[3];
    const float* b2 = (const float*)d_in[4];
    float* out = (float*)d_out;

    char* ws = (char*)d_ws;
    const size_t m16_b = (size_t)B_SZ * H_SZ * 2;        // 67.1 MB
    const size_t m4_b  = (size_t)B_SZ * H_SZ;            // 33.6 MB
    const size_t w1s_b = (size_t)2 * H_SZ * D_SZ * 2;    // 8.4 MB
    const size_t w2p_b = (size_t)2 * C_SZ * H_SZ * 2;    // 1.05 MB
    unsigned short* M16 = (unsigned short*)ws;
    unsigned char*  M4  = (unsigned char*)(ws + m16_b);
    unsigned short* w1s = (unsigned short*)(ws + m16_b + m4_b);
    unsigned short* W2p = (unsigned short*)(ws + m16_b + m4_b + w1s_b);
    unsigned int* counter = (unsigned int*)(ws + m16_b + m4_b + w1s_b + w2p_b);
    unsigned short* xs  = (unsigned short*)(ws + m16_b + m4_b + w1s_b + w2p_b + 256);
    const size_t xs_end = m16_b + m4_b + w1s_b + w2p_b + 256 + (size_t)2 * B_SZ * D_SZ * 2;
    const bool presplit = (ws_size >= xs_end);

    hipMemsetAsync(counter, 0, sizeof(unsigned int), stream);

    k_split2<<<(H_SZ * D_SZ) / 1024, 256, 0, stream>>>(W1, w1s, H_SZ * D_SZ);
    k_split2<<<(C_SZ * H_SZ) / 1024, 256, 0, stream>>>(W2, W2p, C_SZ * H_SZ);

    dim3 g1(H_SZ / 128, B_SZ / 128);   // (16, 128)
    if (presplit) {
        k_split2<<<(B_SZ * D_SZ) / 1024, 256, 0, stream>>>(x, xs, B_SZ * D_SZ);
        k_gemm1_ps<<<g1, 256, 0, stream>>>(xs, w1s, b1, M16, M4, counter);
    } else {
        k_gemm1_mfma<<<g1, 256, 0, stream>>>(x, w1s, b1, M16, M4, counter);
    }

    k_layer2_mfma<<<B_SZ / 16, 512, 0, stream>>>(M16, M4, W2p, b2, out);

    k_finalize<<<1, 1, 0, stream>>>(counter, out);
}

// Round 5
// 590.364 us; speedup vs baseline: 1.7325x; 1.7325x over previous
//
#include <hip/hip_runtime.h>
#include <hip/hip_bf16.h>

#define B_SZ 16384
#define D_SZ 1024
#define H_SZ 2048
#define C_SZ 128
#define T_STEPS 20

typedef __attribute__((ext_vector_type(4))) float f32x4;
typedef __attribute__((ext_vector_type(8))) short bf16x8;

__device__ __forceinline__ void gl_lds16(const void* g, void* l) {
    __builtin_amdgcn_global_load_lds(
        (const __attribute__((address_space(1))) unsigned int*)g,
        (__attribute__((address_space(3))) unsigned int*)l, 16, 0, 0);
}

__device__ __forceinline__ unsigned int lif_mask(float i1) {
    float u = 0.0f;
    unsigned int m = 0;
    #pragma unroll
    for (int t = 0; t < T_STEPS; ++t) {
        u = __fadd_rn(__fmul_rn(0.9f, u), i1);   // match np: separate mul, add
        if (u >= 1.0f) { m |= (1u << t); u = 0.0f; }
    }
    return m;
}

// ---------------- generic fp32 -> 2 bf16 planes splitter (RNE hi, RNE mid) ----------
__global__ void k_split2(const float* __restrict__ src, unsigned short* __restrict__ dst, int n) {
    int i = blockIdx.x * blockDim.x + threadIdx.x;   // float4 index
    float4 v = reinterpret_cast<const float4*>(src)[i];
    float f[4] = {v.x, v.y, v.z, v.w};
    unsigned short h[4], m[4];
    #pragma unroll
    for (int j = 0; j < 4; ++j) {
        __hip_bfloat16 hb = __float2bfloat16(f[j]);
        h[j] = __bfloat16_as_ushort(hb);
        m[j] = __bfloat16_as_ushort(__float2bfloat16(f[j] - __bfloat162float(hb)));
    }
    reinterpret_cast<ushort4*>(dst)[i] = make_ushort4(h[0], h[1], h[2], h[3]);
    reinterpret_cast<ushort4*>(dst + n)[i] = make_ushort4(m[0], m[1], m[2], m[3]);
}

// ---------------- pre-permute W2 planes into MFMA fragment order ----------------
// dst u16 layout: [kt(64)][ch(2)][s(2)][nt(4)][lane(64)][8]
// value = W2p[s][c = ch*64+nt*16+(lane&15)][h = kt*32+(lane>>4)*8 .. +7]
__global__ void k_w2frag(const unsigned short* __restrict__ W2p, unsigned short* __restrict__ W2f) {
    int idx = blockIdx.x * blockDim.x + threadIdx.x;   // 0..65535 (one 8-u16 run each)
    int lane = idx & 63;
    int nt   = (idx >> 6) & 3;
    int s    = (idx >> 8) & 1;
    int ch   = (idx >> 9) & 1;
    int kt   = idx >> 10;
    int c = ch * 64 + nt * 16 + (lane & 15);
    int h = kt * 32 + (lane >> 4) * 8;
    uint4 v = *reinterpret_cast<const uint4*>(W2p + ((size_t)s * C_SZ + c) * H_SZ + h);
    *reinterpret_cast<uint4*>(W2f + (size_t)idx * 8) = v;
}

// x trunc-hi / RNE-mid split of a float pair into two packed bf16x2 words
#define SPLIT2(fe, fo, HW, MW) { \
    unsigned ue = __float_as_uint(fe), uo = __float_as_uint(fo); \
    HW = (uo & 0xffff0000u) | (ue >> 16); \
    float re = (fe) - __uint_as_float(ue & 0xffff0000u); \
    float ro = (fo) - __uint_as_float(uo & 0xffff0000u); \
    MW = (unsigned)__bfloat16_as_ushort(__float2bfloat16(re)) | \
         ((unsigned)__bfloat16_as_ushort(__float2bfloat16(ro)) << 16); }

// ---------------- K1: i1 = x @ W1^T + b1 via 2-split bf16 MFMA, fused LIF -> masks ----
// (round-3 kernel, known-good) A = W1 planes (gload_lds, pre-swizzled source);
// x loaded fp32, split to hi/mid in-reg, swizzled ds_write. 128x128 tile, BK=32.
__global__ __launch_bounds__(256) void k_gemm1_mfma(
    const float* __restrict__ x,
    const unsigned short* __restrict__ w1s,
    const float* __restrict__ b1,
    unsigned short* __restrict__ M16,
    unsigned char* __restrict__ M4,
    unsigned int* __restrict__ spike_count)
{
    __shared__ char lds[32768];
    const int tid  = threadIdx.x;
    const int wv   = tid >> 6;
    const int lane = tid & 63;
    const int l15  = lane & 15;
    const int g    = lane >> 4;
    const int wr   = wv >> 1;
    const int wc   = wv & 1;
    const int hb0  = blockIdx.x * 128;
    const int bb0  = blockIdx.y * 128;

    const int ar   = tid >> 1;
    const int ac0  = (tid & 1) * 16;
    const float* xrow = x + (size_t)(bb0 + ar) * D_SZ + ac0;
    const int asw   = (ar & 7) << 4;
    const int lbase = 16384 + ar * 128 + ac0 * 2;

    f32x4 acc[4][4];
    #pragma unroll
    for (int i = 0; i < 4; ++i)
        #pragma unroll
        for (int j = 0; j < 4; ++j)
            acc[i][j] = (f32x4){0.f, 0.f, 0.f, 0.f};

    for (int k0 = 0; k0 < D_SZ; k0 += 32) {
        float4 av0 = *reinterpret_cast<const float4*>(xrow + k0);
        float4 av1 = *reinterpret_cast<const float4*>(xrow + k0 + 4);
        float4 av2 = *reinterpret_cast<const float4*>(xrow + k0 + 8);
        float4 av3 = *reinterpret_cast<const float4*>(xrow + k0 + 12);
        __syncthreads();
        #pragma unroll
        for (int i = 0; i < 4; ++i) {
            int o   = i * 4096 + wv * 1024 + lane * 16;
            int col = o >> 7;
            int p   = o ^ ((col & 7) << 4);
            int s   = (p >> 6) & 1;
            int kk  = (p & 63) >> 1;
            gl_lds16(w1s + ((size_t)s * H_SZ + hb0 + col) * D_SZ + k0 + kk,
                     lds + (i * 4096 + wv * 1024));
        }
        {
            uint4 hwv, hwv2, mwv, mwv2;
            SPLIT2(av0.x, av0.y, hwv.x,  mwv.x);
            SPLIT2(av0.z, av0.w, hwv.y,  mwv.y);
            SPLIT2(av1.x, av1.y, hwv.z,  mwv.z);
            SPLIT2(av1.z, av1.w, hwv.w,  mwv.w);
            SPLIT2(av2.x, av2.y, hwv2.x, mwv2.x);
            SPLIT2(av2.z, av2.w, hwv2.y, mwv2.y);
            SPLIT2(av3.x, av3.y, hwv2.z, mwv2.z);
            SPLIT2(av3.z, av3.w, hwv2.w, mwv2.w);
            *reinterpret_cast<uint4*>(lds + ((lbase)      ^ asw)) = hwv;
            *reinterpret_cast<uint4*>(lds + ((lbase + 16) ^ asw)) = hwv2;
            *reinterpret_cast<uint4*>(lds + ((lbase + 64) ^ asw)) = mwv;
            *reinterpret_cast<uint4*>(lds + ((lbase + 80) ^ asw)) = mwv2;
        }
        __syncthreads();

        bf16x8 Xh[4], Xm[4];
        #pragma unroll
        for (int n = 0; n < 4; ++n) {
            int c  = wc * 64 + n * 16 + l15;
            int sw = (c & 7) << 4;
            Xh[n] = *reinterpret_cast<const bf16x8*>(lds + (16384 + ((c * 128 + g * 16) ^ sw)));
            Xm[n] = *reinterpret_cast<const bf16x8*>(lds + (16384 + ((c * 128 + 64 + g * 16) ^ sw)));
        }
        #pragma unroll
        for (int m = 0; m < 4; ++m) {
            int r  = wr * 64 + m * 16 + l15;
            int sw = (r & 7) << 4;
            bf16x8 Wh = *reinterpret_cast<const bf16x8*>(lds + ((r * 128 + g * 16) ^ sw));
            bf16x8 Wm = *reinterpret_cast<const bf16x8*>(lds + ((r * 128 + 64 + g * 16) ^ sw));
            #pragma unroll
            for (int n = 0; n < 4; ++n) {
                acc[m][n] = __builtin_amdgcn_mfma_f32_16x16x32_bf16(Wh, Xh[n], acc[m][n], 0, 0, 0);
                acc[m][n] = __builtin_amdgcn_mfma_f32_16x16x32_bf16(Wh, Xm[n], acc[m][n], 0, 0, 0);
                acc[m][n] = __builtin_amdgcn_mfma_f32_16x16x32_bf16(Wm, Xh[n], acc[m][n], 0, 0, 0);
            }
        }
    }

    int spikes = 0;
    #pragma unroll
    for (int m = 0; m < 4; ++m) {
        const int h0l = hb0 + wr * 64 + m * 16 + g * 4;
        float4 bias = *reinterpret_cast<const float4*>(b1 + h0l);
        #pragma unroll
        for (int n = 0; n < 4; ++n) {
            const int b = bb0 + wc * 64 + n * 16 + l15;
            unsigned mk0 = lif_mask(acc[m][n][0] + bias.x);
            unsigned mk1 = lif_mask(acc[m][n][1] + bias.y);
            unsigned mk2 = lif_mask(acc[m][n][2] + bias.z);
            unsigned mk3 = lif_mask(acc[m][n][3] + bias.w);
            spikes += __popc(mk0) + __popc(mk1) + __popc(mk2) + __popc(mk3);
            *reinterpret_cast<uint2*>(M16 + (size_t)b * H_SZ + h0l) =
                make_uint2((mk0 & 0xffffu) | (mk1 << 16),
                           (mk2 & 0xffffu) | (mk3 << 16));
            *reinterpret_cast<unsigned int*>(M4 + (size_t)b * H_SZ + h0l) =
                (mk0 >> 16) | ((mk1 >> 16) << 8) | ((mk2 >> 16) << 16) | ((mk3 >> 16) << 24);
        }
    }
    #pragma unroll
    for (int off = 32; off > 0; off >>= 1)
        spikes += __shfl_down(spikes, off);
    if (lane == 0)
        atomicAdd(spike_count, (unsigned int)spikes);
}

// ---------------- K2: layer 2, LDS-free main loop ----------------
// 512 thr = 8 waves. Wave (tg = w>>1, ch = w&1): 5 timesteps x 64 cols, 16 b-rows.
// B fragments read directly from fragment-ordered W2f (L2-resident, coalesced).
// No barriers / no LDS in main loop. Epilogue: LDS transpose + fused LIF.
#define TLV(b, c, t) sm_f32[(((b) * 32 + (c)) * 21) + (t)]
__global__ __launch_bounds__(512) void k_layer2_mfma(
    const unsigned short* __restrict__ M16,
    const unsigned char* __restrict__ M4,
    const unsigned short* __restrict__ W2f,   // fragment-ordered
    const float* __restrict__ b2,
    float* __restrict__ out)
{
    __shared__ __align__(16) char smem[43008];
    float* sm_f32 = (float*)smem;

    const int tid  = threadIdx.x;
    const int w    = tid >> 6;
    const int tg   = w >> 1;          // t in [tg*5, tg*5+5)
    const int ch   = w & 1;           // cols [ch*64, ch*64+64)
    const int lane = tid & 63;
    const int l15  = lane & 15;
    const int g    = lane >> 4;
    const int b0   = blockIdx.x * 16;
    const int t0   = tg * 5;

    f32x4 acc[4][5];
    #pragma unroll
    for (int n = 0; n < 4; ++n)
        #pragma unroll
        for (int t = 0; t < 5; ++t)
            acc[n][t] = (f32x4){0.f, 0.f, 0.f, 0.f};

    const unsigned short* m16row = M16 + (size_t)(b0 + l15) * H_SZ;
    const unsigned char*  m4row  = M4  + (size_t)(b0 + l15) * H_SZ;
    const unsigned short* fbase  = W2f + (size_t)ch * 4096 + (size_t)lane * 8;

    for (int kt = 0; kt < 64; ++kt) {
        const int h0 = kt * 32;
        uint4 w16 = *reinterpret_cast<const uint4*>(m16row + h0 + g * 8);
        uint2 w4 = make_uint2(0u, 0u);
        if (tg == 3)
            w4 = *reinterpret_cast<const uint2*>(m4row + h0 + g * 8);

        bf16x8 bf[2][4];
        {
            const unsigned short* fk = fbase + (size_t)kt * 8192;
            #pragma unroll
            for (int s = 0; s < 2; ++s)
                #pragma unroll
                for (int nt = 0; nt < 4; ++nt)
                    bf[s][nt] = *reinterpret_cast<const bf16x8*>(fk + (s * 4 + nt) * 512);
        }

        #pragma unroll
        for (int tl_ = 0; tl_ < 5; ++tl_) {
            const int t = t0 + tl_;
            union { bf16x8 v; unsigned int u[4]; } A;
            if (t < 16) {
                A.u[0] = ((w16.x >> t) & 0x10001u) * 0x3F80u;
                A.u[1] = ((w16.y >> t) & 0x10001u) * 0x3F80u;
                A.u[2] = ((w16.z >> t) & 0x10001u) * 0x3F80u;
                A.u[3] = ((w16.w >> t) & 0x10001u) * 0x3F80u;
            } else {
                const int tt = t - 16;
                unsigned x0 = (w4.x >> tt)        & 0x101u;
                unsigned x1 = (w4.x >> (16 + tt)) & 0x101u;
                unsigned x2 = (w4.y >> tt)        & 0x101u;
                unsigned x3 = (w4.y >> (16 + tt)) & 0x101u;
                A.u[0] = ((x0 * 0x0101u) & 0x10001u) * 0x3F80u;
                A.u[1] = ((x1 * 0x0101u) & 0x10001u) * 0x3F80u;
                A.u[2] = ((x2 * 0x0101u) & 0x10001u) * 0x3F80u;
                A.u[3] = ((x3 * 0x0101u) & 0x10001u) * 0x3F80u;
            }
            #pragma unroll
            for (int nt = 0; nt < 4; ++nt) {
                acc[nt][tl_] = __builtin_amdgcn_mfma_f32_16x16x32_bf16(A.v, bf[0][nt], acc[nt][tl_], 0, 0, 0);
                acc[nt][tl_] = __builtin_amdgcn_mfma_f32_16x16x32_bf16(A.v, bf[1][nt], acc[nt][tl_], 0, 0, 0);
            }
        }
    }

    // epilogue: 4 c-chunks of 32; transpose through LDS, then LIF per (b,c)
    #pragma unroll
    for (int q = 0; q < 4; ++q) {
        __syncthreads();
        if (ch == (q >> 1)) {
            #pragma unroll
            for (int u = 0; u < 2; ++u) {
                const int nt = (q & 1) * 2 + u;
                const int cl = nt * 16 + l15 - (q & 1) * 32;   // 0..31
                #pragma unroll
                for (int tl_ = 0; tl_ < 5; ++tl_)
                    #pragma unroll
                    for (int j = 0; j < 4; ++j)
                        TLV(g * 4 + j, cl, t0 + tl_) = acc[nt][tl_][j];
            }
        }
        __syncthreads();
        {
            const int cl = tid & 31;
            const int bl = tid >> 5;
            const int c  = q * 32 + cl;
            const float bias = b2[c];
            float u2 = 0.0f; int cnt = 0;
            #pragma unroll
            for (int t = 0; t < T_STEPS; ++t) {
                float X = TLV(bl, cl, t) + bias;
                u2 = __fadd_rn(__fmul_rn(0.9f, u2), X);
                if (u2 >= 1.0f) { cnt++; u2 = 0.0f; }
            }
            out[(size_t)(b0 + bl) * C_SZ + c] = (float)cnt / 20.0f;
        }
    }
}

// ---------------- K3: mean_spikes = total / (B * T) ----------------
__global__ void k_finalize(const unsigned int* __restrict__ spike_count, float* __restrict__ out) {
    out[(size_t)B_SZ * C_SZ] = (float)(*spike_count) / (float)((size_t)B_SZ * T_STEPS);
}

extern "C" void kernel_launch(void* const* d_in, const int* in_sizes, int n_in,
                              void* d_out, int out_size, void* d_ws, size_t ws_size,
                              hipStream_t stream) {
    const float* x  = (const float*)d_in[0];
    const float* W1 = (const float*)d_in[1];
    const float* b1 = (const float*)d_in[2];
    const float* W2 = (const float*)d_in[3];
    const float* b2 = (const float*)d_in[4];
    float* out = (float*)d_out;

    char* ws = (char*)d_ws;
    const size_t m16_b = (size_t)B_SZ * H_SZ * 2;        // 67.1 MB
    const size_t m4_b  = (size_t)B_SZ * H_SZ;            // 33.6 MB
    const size_t w1s_b = (size_t)2 * H_SZ * D_SZ * 2;    // 8.4 MB
    const size_t w2p_b = (size_t)2 * C_SZ * H_SZ * 2;    // 1.05 MB
    unsigned short* M16 = (unsigned short*)ws;
    unsigned char*  M4  = (unsigned char*)(ws + m16_b);
    unsigned short* w1s = (unsigned short*)(ws + m16_b + m4_b);
    unsigned short* W2p = (unsigned short*)(ws + m16_b + m4_b + w1s_b);
    unsigned short* W2f = (unsigned short*)(ws + m16_b + m4_b + w1s_b + w2p_b);
    unsigned int* counter = (unsigned int*)(ws + m16_b + m4_b + w1s_b + w2p_b + w2p_b);

    hipMemsetAsync(counter, 0, sizeof(unsigned int), stream);

    k_split2<<<(H_SZ * D_SZ) / 1024, 256, 0, stream>>>(W1, w1s, H_SZ * D_SZ);
    k_split2<<<(C_SZ * H_SZ) / 1024, 256, 0, stream>>>(W2, W2p, C_SZ * H_SZ);
    k_w2frag<<<256, 256, 0, stream>>>(W2p, W2f);

    dim3 g1(H_SZ / 128, B_SZ / 128);   // (16, 128)
    k_gemm1_mfma<<<g1, 256, 0, stream>>>(x, w1s, b1, M16, M4, counter);

    k_layer2_mfma<<<B_SZ / 16, 512, 0, stream>>>(M16, M4, W2f, b2, out);

    k_finalize<<<1, 1, 0, stream>>>(counter, out);
}